// Round 22
// baseline (319.618 us; speedup 1.0000x reference)
//
#include <hip/hip_runtime.h>
#include <hip/hip_bf16.h>
#include <cstdint>

#define BB 128
#define LL 28
#define FF 28
#define DM 256
#define DI 512
#define DS 16
#define DR 16
#define KK 3
#define NLAYER 5
#define NOUT 10
#define NTOK (BB * LL)      // 3584
#define NDBC (DR + 2 * DS)  // 48

#define N_INW (NLAYER * 2 * DI * DM)   // 1310720
#define N_OPW (NLAYER * DM * DI)       // 655360
#define N_XPW (NLAYER * NDBC * DI)     // 122880
#define CAST_BLOCKS ((N_INW + N_OPW + N_XPW) / 1024)   // 2040
#define INPROJ_BLOCKS ((DM / 64) * (NTOK / 64))        // 224

typedef __attribute__((ext_vector_type(8))) short bf16x8;
typedef __attribute__((ext_vector_type(4))) float f32x4;

__device__ __forceinline__ float sigmoidf_(float x) { return 1.0f / (1.0f + __expf(-x)); }
__device__ __forceinline__ float siluf_(float x) { return x * sigmoidf_(x); }
// fast softplus: |err| ~1e-7 abs, tolerance is 4.9e-4
__device__ __forceinline__ float softplus_fast(float x) {
    return (x > 20.0f) ? x : __logf(1.0f + __expf(x));
}

// ---------------- prep: weight casts + fp32 input projection (verified R21) ----------------
__global__ __launch_bounds__(256) void k_prep(
        const float* __restrict__ inw, const float* __restrict__ opw,
        const float* __restrict__ xpw,
        __hip_bfloat16* __restrict__ inwb, __hip_bfloat16* __restrict__ opwb,
        __hip_bfloat16* __restrict__ xpwb,
        const float* __restrict__ x, const float* __restrict__ ipw,
        float* __restrict__ h, __hip_bfloat16* __restrict__ hb) {
    const int bid = blockIdx.x;
    if (bid < CAST_BLOCKS) {
        int i = (bid * 256 + threadIdx.x) * 4;
        const float* s; __hip_bfloat16* d; int off;
        if (i < N_INW) { s = inw; d = inwb; off = i; }
        else if (i < N_INW + N_OPW) { s = opw; d = opwb; off = i - N_INW; }
        else if (i < N_INW + N_OPW + N_XPW) { s = xpw; d = xpwb; off = i - N_INW - N_OPW; }
        else return;
        float4 v = *(const float4*)&s[off];
        d[off + 0] = __float2bfloat16(v.x);
        d[off + 1] = __float2bfloat16(v.y);
        d[off + 2] = __float2bfloat16(v.z);
        d[off + 3] = __float2bfloat16(v.w);
    } else {
        constexpr int K = FF, N = DM;
        __shared__ float As[16][68];
        __shared__ float Ws[16][68];
        const int b2 = bid - CAST_BLOCKS;
        const int bm = (b2 >> 2) * 64;
        const int bn = (b2 & 3) * 64;
        const int tid = threadIdx.x;
        const int kk = tid & 15, row = tid >> 4;
        const int tx = tid & 15, ty = tid >> 4;
        float acc[4][4];
        #pragma unroll
        for (int i = 0; i < 4; ++i)
            #pragma unroll
            for (int j = 0; j < 4; ++j) acc[i][j] = 0.f;
        for (int k0 = 0; k0 < K; k0 += 16) {
            const int k = k0 + kk;
            const bool kok = (k < K);
            #pragma unroll
            for (int r = 0; r < 4; ++r) {
                As[kk][r * 16 + row] = kok ? x[(size_t)(bm + r * 16 + row) * K + k] : 0.f;
                Ws[kk][r * 16 + row] = kok ? ipw[(size_t)(bn + r * 16 + row) * K + k] : 0.f;
            }
            __syncthreads();
            #pragma unroll
            for (int k2 = 0; k2 < 16; ++k2) {
                float a[4], b[4];
                #pragma unroll
                for (int i = 0; i < 4; ++i) a[i] = As[k2][ty * 4 + i];
                #pragma unroll
                for (int j = 0; j < 4; ++j) b[j] = Ws[k2][tx * 4 + j];
                #pragma unroll
                for (int i = 0; i < 4; ++i)
                    #pragma unroll
                    for (int j = 0; j < 4; ++j) acc[i][j] += a[i] * b[j];
            }
            __syncthreads();
        }
        #pragma unroll
        for (int i = 0; i < 4; ++i) {
            const int m = bm + ty * 4 + i;
            #pragma unroll
            for (int j = 0; j < 4; ++j) {
                const int n = bn + tx * 4 + j;
                float v = acc[i][j];
                h[(size_t)m * N + n] = v;
                hb[(size_t)m * N + n] = __float2bfloat16(v);
            }
        }
    }
}

// ---------------- xz GEMM + fused conv/silu epilogues (verified R12/R21) ----------------
__global__ __launch_bounds__(256) void k_xz_conv(
        const __hip_bfloat16* __restrict__ hb,    // [NTOK][DM]
        const __hip_bfloat16* __restrict__ inw_l, // [1024][DM]
        const float* __restrict__ convw_l,        // [DI][KK]
        const float* __restrict__ convb_l,        // [DI]
        __hip_bfloat16* __restrict__ ub,          // [NTOK][DI]
        __hip_bfloat16* __restrict__ gzb) {       // [NTOK][DI]
    __shared__ __align__(16) __hip_bfloat16 As[32][264];
    __shared__ __align__(16) __hip_bfloat16 Ws[64][264];
    __shared__ __align__(16) __hip_bfloat16 xbt[32][72];

    const int b = blockIdx.y;
    const int n0 = blockIdx.x * 64;
    const int t = threadIdx.x;
    const int wave = t >> 6, lane = t & 63;
    const int rla = lane & 15, koff = (lane >> 4) * 8;
    const int lrow = (lane >> 4) * 4, lcol = lane & 15;

    for (int i = t; i < 28 * 32; i += 256) {
        const int r = i >> 5, c = (i & 31) * 8;
        *(int4*)&As[r][c] = *(const int4*)&hb[(size_t)(b * LL + r) * DM + c];
    }
    for (int i = t; i < 64 * 32; i += 256) {
        const int r = i >> 5, c = (i & 31) * 8;
        *(int4*)&Ws[r][c] = *(const int4*)&inw_l[(size_t)(n0 + r) * DM + c];
    }
    __syncthreads();

    f32x4 acc0 = {}, acc1 = {};
    #pragma unroll
    for (int ks = 0; ks < 8; ++ks) {
        bf16x8 bf = *(const bf16x8*)&Ws[wave * 16 + rla][ks * 32 + koff];
        bf16x8 a0 = *(const bf16x8*)&As[rla][ks * 32 + koff];
        bf16x8 a1 = *(const bf16x8*)&As[16 + rla][ks * 32 + koff];
        acc0 = __builtin_amdgcn_mfma_f32_16x16x32_bf16(a0, bf, acc0, 0, 0, 0);
        acc1 = __builtin_amdgcn_mfma_f32_16x16x32_bf16(a1, bf, acc1, 0, 0, 0);
    }

    const int ncol = wave * 16 + lcol;
    if (n0 < DI) {
        #pragma unroll
        for (int r = 0; r < 4; ++r) {
            const int m0 = lrow + r, m1 = 16 + lrow + r;
            xbt[m0][ncol] = __float2bfloat16(acc0[r]);
            if (m1 < LL) xbt[m1][ncol] = __float2bfloat16(acc1[r]);
        }
        __syncthreads();
        const int col = t & 63, lg = t >> 6;
        const int di = n0 + col;
        const float c0 = convw_l[di * KK + 0];
        const float c1 = convw_l[di * KK + 1];
        const float c2 = convw_l[di * KK + 2];
        const float cbv = convb_l[di];
        const int l0 = lg * 7;
        float xm2 = (l0 >= 2) ? __bfloat162float(xbt[l0 - 2][col]) : 0.f;
        float xm1 = (l0 >= 1) ? __bfloat162float(xbt[l0 - 1][col]) : 0.f;
        #pragma unroll
        for (int j = 0; j < 7; ++j) {
            const int l = l0 + j;
            const float x0 = __bfloat162float(xbt[l][col]);
            const float v = siluf_(cbv + c0 * xm2 + c1 * xm1 + c2 * x0);
            xm2 = xm1; xm1 = x0;
            ub[(size_t)(b * LL + l) * DI + di] = __float2bfloat16(v);
        }
    } else {
        const int zc = n0 - DI + ncol;
        #pragma unroll
        for (int r = 0; r < 4; ++r) {
            const int m0 = lrow + r, m1 = 16 + lrow + r;
            gzb[(size_t)(b * LL + m0) * DI + zc] = __float2bfloat16(siluf_(acc0[r]));
            if (m1 < LL)
                gzb[(size_t)(b * LL + m1) * DI + zc] = __float2bfloat16(siluf_(acc1[r]));
        }
    }
}

// ---------------- scan with STAGED fused x_proj ----------------
// Grid (BB, 8), 256 thr = 4 waves, LDS 48.3 KB -> 3 blocks/CU.
// Full-width u staged once into Us[32][520] (xproj-compatible padded layout);
// xproj's 6 MFMA wave-tiles read A-frags from LDS (R19's direct-global mistake
// fixed); delta phase + scan body are the verified R12 forms (R11's in-loop
// softplus mistake fixed). y overwrites Us columns in place (wave-lockstep).
// Rows 28..31 of Us are uninitialized; they feed only discarded C rows.
__global__ __launch_bounds__(256) void k_scan_fx(
        const __hip_bfloat16* __restrict__ ub,    // [NTOK][DI]
        const __hip_bfloat16* __restrict__ gzb,   // [NTOK][DI]
        const __hip_bfloat16* __restrict__ xpw_l, // [NDBC][DI]
        const float* __restrict__ dtw_l,          // [DI][DR]
        const float* __restrict__ dtb_l,          // [DI]
        const float* __restrict__ alog_l,         // [DI][DS]
        const float* __restrict__ Dvec_l,         // [DI]
        __hip_bfloat16* __restrict__ yb) {        // [NTOK][DI]
    __shared__ __align__(16) __hip_bfloat16 Us[32][520];   // 33.3 KB (u, then y)
    __shared__ __align__(16) __hip_bfloat16 sgz[LL][64];   // 3.5 KB
    __shared__ float sdbc[LL][NDBC];                       // 5.25 KB
    __shared__ float sdelta[LL][64];                       // 7 KB

    const int b = blockIdx.x;
    const int cg = blockIdx.y;
    const int di0 = cg * 64;
    const int t = threadIdx.x;
    const int wave = t >> 6, lane = t & 63;
    const int rla = lane & 15, koff = (lane >> 4) * 8;
    const int lrow = (lane >> 4) * 4, lcol = lane & 15;

    // stage full-width u rows (28 x 512 bf16) and this block's gz slab
    for (int i = t; i < 28 * 64; i += 256) {
        const int r = i >> 6, c = (i & 63) * 8;
        *(int4*)&Us[r][c] = *(const int4*)&ub[(size_t)(b * LL + r) * DI + c];
    }
    for (int i = t; i < 224; i += 256) {
        const int r = i >> 3, c = (i & 7) * 8;
        *(int4*)&sgz[r][c] = *(const int4*)&gzb[(size_t)(b * LL + r) * DI + di0 + c];
    }

    // phase-1 constants (global reads, no LDS dependency)
    float wrow[DR];
    {
        const float4* w4 = (const float4*)(dtw_l + (size_t)(di0 + lane) * DR);
        #pragma unroll
        for (int q = 0; q < DR / 4; ++q) {
            float4 v = w4[q];
            wrow[q * 4 + 0] = v.x; wrow[q * 4 + 1] = v.y;
            wrow[q * 4 + 2] = v.z; wrow[q * 4 + 3] = v.w;
        }
    }
    const float dbias = dtb_l[di0 + lane];
    __syncthreads();

    // x_proj: dbc = u @ xpw^T (M=28->32, N=48, K=512); 6 staged-LDS wave-tiles
    #pragma unroll
    for (int cc = 0; cc < 2; ++cc) {
        const int c = wave + cc * 4;
        if (c < 6) {
            const int mt = c & 1, nt = c >> 1;
            f32x4 acc = {};
            #pragma unroll
            for (int ks = 0; ks < 16; ++ks) {
                bf16x8 bf = *(const bf16x8*)&xpw_l[(size_t)(nt * 16 + rla) * DI + ks * 32 + koff];
                bf16x8 af = *(const bf16x8*)&Us[mt * 16 + rla][ks * 32 + koff];
                acc = __builtin_amdgcn_mfma_f32_16x16x32_bf16(af, bf, acc, 0, 0, 0);
            }
            #pragma unroll
            for (int r = 0; r < 4; ++r) {
                const int m = mt * 16 + lrow + r;
                if (m < LL) sdbc[m][nt * 16 + lcol] = acc[r];
            }
        }
    }
    __syncthreads();

    // phase 1: delta (7 per thread), fast softplus
    #pragma unroll
    for (int j = 0; j < 7; ++j) {
        const int l = wave * 7 + j;
        const float4 q0 = *(const float4*)&sdbc[l][0];
        const float4 q1 = *(const float4*)&sdbc[l][4];
        const float4 q2 = *(const float4*)&sdbc[l][8];
        const float4 q3 = *(const float4*)&sdbc[l][12];
        float d0 = wrow[0] * q0.x + wrow[1] * q0.y + wrow[2] * q0.z + wrow[3] * q0.w;
        float d1 = wrow[4] * q1.x + wrow[5] * q1.y + wrow[6] * q1.z + wrow[7] * q1.w;
        float d2 = wrow[8] * q2.x + wrow[9] * q2.y + wrow[10] * q2.z + wrow[11] * q2.w;
        float d3 = wrow[12] * q3.x + wrow[13] * q3.y + wrow[14] * q3.z + wrow[15] * q3.w;
        sdelta[l][lane] = softplus_fast(((d0 + d1) + (d2 + d3)) + dbias);
    }

    // phase-2 constants: thread = (channel, state-quad)
    const int c = t >> 2, sq = t & 3;
    const int di = di0 + c;
    float4 aq = *(const float4*)&alog_l[(size_t)di * DS + sq * 4];
    const float A0 = -__expf(aq.x), A1 = -__expf(aq.y);
    const float A2 = -__expf(aq.z), A3 = -__expf(aq.w);
    const float Dd = Dvec_l[di];

    __syncthreads();

    float st0 = 0.f, st1 = 0.f, st2 = 0.f, st3 = 0.f;
    #pragma unroll 2
    for (int l = 0; l < LL; ++l) {
        const float d = sdelta[l][c];
        const float uu = __bfloat162float(Us[l][di0 + c]);
        const float du = d * uu;
        const float4 Bq = *(const float4*)&sdbc[l][DR + sq * 4];
        const float4 Cq = *(const float4*)&sdbc[l][DR + DS + sq * 4];
        st0 = __expf(d * A0) * st0 + du * Bq.x;
        st1 = __expf(d * A1) * st1 + du * Bq.y;
        st2 = __expf(d * A2) * st2 + du * Bq.z;
        st3 = __expf(d * A3) * st3 + du * Bq.w;
        float yp = st0 * Cq.x + st1 * Cq.y + st2 * Cq.z + st3 * Cq.w;
        yp += __shfl_xor(yp, 1);
        yp += __shfl_xor(yp, 2);
        if (sq == 0) {
            const float g = __bfloat162float(sgz[l][c]);
            Us[l][di0 + c] = __float2bfloat16((yp + uu * Dd) * g);   // y in place
        }
    }
    __syncthreads();

    for (int i = t; i < 224; i += 256) {
        const int r = i >> 3, cc2 = (i & 7) * 8;
        *(int4*)&yb[(size_t)(b * LL + r) * DI + di0 + cc2] = *(const int4*)&Us[r][di0 + cc2];
    }
}

// ---------------- out_proj (R21); LAST fuses pool+cls ----------------
template <int LAST>
__global__ __launch_bounds__(256) void k_outproj(
        const __hip_bfloat16* __restrict__ yb,    // [NTOK][DI]
        const __hip_bfloat16* __restrict__ opw_l, // [DM][DI]
        float* __restrict__ h,                    // [NTOK][DM]
        __hip_bfloat16* __restrict__ hb,
        const float* __restrict__ clsw,           // [NOUT][DM]
        float* __restrict__ out) {                // [BB][NOUT] (pre-zeroed)
    __shared__ __align__(16) __hip_bfloat16 As[32][520];

    const int b = blockIdx.y;
    const int n0 = blockIdx.x * 32;
    const int t = threadIdx.x;
    const int wave = t >> 6, lane = t & 63;
    const int rla = lane & 15, koff = (lane >> 4) * 8;
    const int lrow = (lane >> 4) * 4, lcol = lane & 15;

    for (int i = t; i < 28 * 64; i += 256) {
        const int r = i >> 6, c = (i & 63) * 8;
        *(int4*)&As[r][c] = *(const int4*)&yb[(size_t)(b * LL + r) * DI + c];
    }
    __syncthreads();

    const int mt = wave & 1, nt = wave >> 1;
    f32x4 acc = {};
    #pragma unroll
    for (int ks = 0; ks < 16; ++ks) {
        bf16x8 bf = *(const bf16x8*)&opw_l[(size_t)(n0 + nt * 16 + rla) * DI + ks * 32 + koff];
        bf16x8 af = *(const bf16x8*)&As[mt * 16 + rla][ks * 32 + koff];
        acc = __builtin_amdgcn_mfma_f32_16x16x32_bf16(af, bf, acc, 0, 0, 0);
    }
    #pragma unroll
    for (int r = 0; r < 4; ++r) {
        const int m = mt * 16 + lrow + r;
        if (m < LL) {
            const int n = n0 + nt * 16 + lcol;
            const size_t idx = (size_t)(b * LL + m) * DM + n;
            const float v = h[idx] + acc[r];
            h[idx] = v;
            hb[idx] = __float2bfloat16(v);
        }
    }

    if (LAST) {
        __shared__ float pooled[32];
        __syncthreads();
        if (t < 32) {
            float p = 0.f;
            for (int l = 0; l < LL; ++l) p += h[(size_t)(b * LL + l) * DM + n0 + t];
            pooled[t] = p * (1.0f / LL);
        }
        __syncthreads();
        if (t < NOUT) {
            const float* cw = clsw + t * DM + n0;
            float a0 = 0.f, a1 = 0.f, a2 = 0.f, a3 = 0.f;
            #pragma unroll
            for (int n = 0; n < 32; n += 4) {
                a0 += pooled[n + 0] * cw[n + 0];
                a1 += pooled[n + 1] * cw[n + 1];
                a2 += pooled[n + 2] * cw[n + 2];
                a3 += pooled[n + 3] * cw[n + 3];
            }
            atomicAdd(&out[b * NOUT + t], (a0 + a1) + (a2 + a3));
        }
    }
}

extern "C" void kernel_launch(void* const* d_in, const int* in_sizes, int n_in,
                              void* d_out, int out_size, void* d_ws, size_t ws_size,
                              hipStream_t stream) {
    const float* x       = (const float*)d_in[0];
    const float* ipw     = (const float*)d_in[1];
    const float* inw     = (const float*)d_in[2];
    const float* convw   = (const float*)d_in[3];
    const float* convb   = (const float*)d_in[4];
    const float* xpw     = (const float*)d_in[5];
    const float* dtw     = (const float*)d_in[6];
    const float* dtb     = (const float*)d_in[7];
    const float* alog    = (const float*)d_in[8];
    const float* Dvec    = (const float*)d_in[9];
    const float* opw     = (const float*)d_in[10];
    const float* clsw    = (const float*)d_in[11];
    float* out = (float*)d_out;

    float* h = (float*)d_ws;                             // NTOK*DM f32
    __hip_bfloat16* hb   = (__hip_bfloat16*)(h + (size_t)NTOK * DM);
    __hip_bfloat16* ub   = hb + (size_t)NTOK * DM;
    __hip_bfloat16* gzb  = ub + (size_t)NTOK * DI;
    __hip_bfloat16* yb   = gzb + (size_t)NTOK * DI;
    __hip_bfloat16* inwb = yb + (size_t)NTOK * DI;
    __hip_bfloat16* opwb = inwb + N_INW;
    __hip_bfloat16* xpwb = opwb + N_OPW;

    // zero out (accumulated via atomics in the last out_proj)
    hipMemsetAsync(out, 0, (size_t)BB * NOUT * sizeof(float), stream);

    hipLaunchKernelGGL(k_prep, dim3(CAST_BLOCKS + INPROJ_BLOCKS), dim3(256), 0, stream,
                       inw, opw, xpw, inwb, opwb, xpwb, x, ipw, h, hb);

    for (int layer = 0; layer < NLAYER; ++layer) {
        const __hip_bfloat16* inwb_l = inwb + (size_t)layer * 2 * DI * DM;
        const __hip_bfloat16* xpwb_l = xpwb + (size_t)layer * NDBC * DI;
        const __hip_bfloat16* opwb_l = opwb + (size_t)layer * DM * DI;
        const float* convw_l = convw + (size_t)layer * DI * KK;
        const float* convb_l = convb + (size_t)layer * DI;
        const float* dtw_l   = dtw  + (size_t)layer * DI * DR;
        const float* dtb_l   = dtb  + (size_t)layer * DI;
        const float* alog_l  = alog + (size_t)layer * DI * DS;
        const float* Dvec_l  = Dvec + (size_t)layer * DI;

        hipLaunchKernelGGL(k_xz_conv, dim3(16, BB), dim3(256), 0, stream,
                           hb, inwb_l, convw_l, convb_l, ub, gzb);

        hipLaunchKernelGGL(k_scan_fx, dim3(BB, 8), dim3(256), 0, stream,
                           ub, gzb, xpwb_l, dtw_l, dtb_l, alog_l, Dvec_l, yb);

        if (layer < NLAYER - 1) {
            hipLaunchKernelGGL((k_outproj<0>), dim3(8, BB), dim3(256), 0, stream,
                               yb, opwb_l, h, hb, clsw, out);
        } else {
            hipLaunchKernelGGL((k_outproj<1>), dim3(8, BB), dim3(256), 0, stream,
                               yb, opwb_l, h, hb, clsw, out);
        }
    }
}

// Round 23
// 279.867 us; speedup vs baseline: 1.1420x; 1.1420x over previous
//
#include <hip/hip_runtime.h>
#include <hip/hip_bf16.h>
#include <cstdint>

#define BB 128
#define LL 28
#define FF 28
#define DM 256
#define DI 512
#define DS 16
#define DR 16
#define KK 3
#define NLAYER 5
#define NOUT 10
#define NTOK (BB * LL)      // 3584
#define NDBC (DR + 2 * DS)  // 48

#define N_INW (NLAYER * 2 * DI * DM)   // 1310720
#define N_OPW (NLAYER * DM * DI)       // 655360
#define N_XPW (NLAYER * NDBC * DI)     // 122880
#define CAST_BLOCKS ((N_INW + N_OPW + N_XPW) / 1024)   // 2040
#define INPROJ_BLOCKS ((DM / 64) * (NTOK / 64))        // 224

typedef __attribute__((ext_vector_type(8))) short bf16x8;
typedef __attribute__((ext_vector_type(4))) float f32x4;

__device__ __forceinline__ float sigmoidf_(float x) { return 1.0f / (1.0f + __expf(-x)); }
__device__ __forceinline__ float siluf_(float x) { return x * sigmoidf_(x); }
// fast softplus: |err| ~1e-7 abs, tolerance is 4.9e-4
__device__ __forceinline__ float softplus_fast(float x) {
    return (x > 20.0f) ? x : __logf(1.0f + __expf(x));
}

// ---------------- prep: weight casts + fp32 input projection ----------------
__global__ __launch_bounds__(256) void k_prep(
        const float* __restrict__ inw, const float* __restrict__ opw,
        const float* __restrict__ xpw,
        __hip_bfloat16* __restrict__ inwb, __hip_bfloat16* __restrict__ opwb,
        __hip_bfloat16* __restrict__ xpwb,
        const float* __restrict__ x, const float* __restrict__ ipw,
        float* __restrict__ h, __hip_bfloat16* __restrict__ hb) {
    const int bid = blockIdx.x;
    if (bid < CAST_BLOCKS) {
        int i = (bid * 256 + threadIdx.x) * 4;
        const float* s; __hip_bfloat16* d; int off;
        if (i < N_INW) { s = inw; d = inwb; off = i; }
        else if (i < N_INW + N_OPW) { s = opw; d = opwb; off = i - N_INW; }
        else if (i < N_INW + N_OPW + N_XPW) { s = xpw; d = xpwb; off = i - N_INW - N_OPW; }
        else return;
        float4 v = *(const float4*)&s[off];
        d[off + 0] = __float2bfloat16(v.x);
        d[off + 1] = __float2bfloat16(v.y);
        d[off + 2] = __float2bfloat16(v.z);
        d[off + 3] = __float2bfloat16(v.w);
    } else {
        constexpr int K = FF, N = DM;
        __shared__ float As[16][68];
        __shared__ float Ws[16][68];
        const int b2 = bid - CAST_BLOCKS;
        const int bm = (b2 >> 2) * 64;
        const int bn = (b2 & 3) * 64;
        const int tid = threadIdx.x;
        const int kk = tid & 15, row = tid >> 4;
        const int tx = tid & 15, ty = tid >> 4;
        float acc[4][4];
        #pragma unroll
        for (int i = 0; i < 4; ++i)
            #pragma unroll
            for (int j = 0; j < 4; ++j) acc[i][j] = 0.f;
        for (int k0 = 0; k0 < K; k0 += 16) {
            const int k = k0 + kk;
            const bool kok = (k < K);
            #pragma unroll
            for (int r = 0; r < 4; ++r) {
                As[kk][r * 16 + row] = kok ? x[(size_t)(bm + r * 16 + row) * K + k] : 0.f;
                Ws[kk][r * 16 + row] = kok ? ipw[(size_t)(bn + r * 16 + row) * K + k] : 0.f;
            }
            __syncthreads();
            #pragma unroll
            for (int k2 = 0; k2 < 16; ++k2) {
                float a[4], b[4];
                #pragma unroll
                for (int i = 0; i < 4; ++i) a[i] = As[k2][ty * 4 + i];
                #pragma unroll
                for (int j = 0; j < 4; ++j) b[j] = Ws[k2][tx * 4 + j];
                #pragma unroll
                for (int i = 0; i < 4; ++i)
                    #pragma unroll
                    for (int j = 0; j < 4; ++j) acc[i][j] += a[i] * b[j];
            }
            __syncthreads();
        }
        #pragma unroll
        for (int i = 0; i < 4; ++i) {
            const int m = bm + ty * 4 + i;
            #pragma unroll
            for (int j = 0; j < 4; ++j) {
                const int n = bn + tx * 4 + j;
                float v = acc[i][j];
                h[(size_t)m * N + n] = v;
                hb[(size_t)m * N + n] = __float2bfloat16(v);
            }
        }
    }
}

// ---------------- xz GEMM + fused conv/silu epilogues ----------------
__global__ __launch_bounds__(256) void k_xz_conv(
        const __hip_bfloat16* __restrict__ hb,    // [NTOK][DM]
        const __hip_bfloat16* __restrict__ inw_l, // [1024][DM]
        const float* __restrict__ convw_l,        // [DI][KK]
        const float* __restrict__ convb_l,        // [DI]
        __hip_bfloat16* __restrict__ ub,          // [NTOK][DI]
        __hip_bfloat16* __restrict__ gzb) {       // [NTOK][DI]
    __shared__ __align__(16) __hip_bfloat16 As[32][264];
    __shared__ __align__(16) __hip_bfloat16 Ws[64][264];
    __shared__ __align__(16) __hip_bfloat16 xbt[32][72];

    const int b = blockIdx.y;
    const int n0 = blockIdx.x * 64;
    const int t = threadIdx.x;
    const int wave = t >> 6, lane = t & 63;
    const int rla = lane & 15, koff = (lane >> 4) * 8;
    const int lrow = (lane >> 4) * 4, lcol = lane & 15;

    for (int i = t; i < 28 * 32; i += 256) {
        const int r = i >> 5, c = (i & 31) * 8;
        *(int4*)&As[r][c] = *(const int4*)&hb[(size_t)(b * LL + r) * DM + c];
    }
    for (int i = t; i < 64 * 32; i += 256) {
        const int r = i >> 5, c = (i & 31) * 8;
        *(int4*)&Ws[r][c] = *(const int4*)&inw_l[(size_t)(n0 + r) * DM + c];
    }
    __syncthreads();

    f32x4 acc0 = {}, acc1 = {};
    #pragma unroll
    for (int ks = 0; ks < 8; ++ks) {
        bf16x8 bf = *(const bf16x8*)&Ws[wave * 16 + rla][ks * 32 + koff];
        bf16x8 a0 = *(const bf16x8*)&As[rla][ks * 32 + koff];
        bf16x8 a1 = *(const bf16x8*)&As[16 + rla][ks * 32 + koff];
        acc0 = __builtin_amdgcn_mfma_f32_16x16x32_bf16(a0, bf, acc0, 0, 0, 0);
        acc1 = __builtin_amdgcn_mfma_f32_16x16x32_bf16(a1, bf, acc1, 0, 0, 0);
    }

    const int ncol = wave * 16 + lcol;
    if (n0 < DI) {
        #pragma unroll
        for (int r = 0; r < 4; ++r) {
            const int m0 = lrow + r, m1 = 16 + lrow + r;
            xbt[m0][ncol] = __float2bfloat16(acc0[r]);
            if (m1 < LL) xbt[m1][ncol] = __float2bfloat16(acc1[r]);
        }
        __syncthreads();
        const int col = t & 63, lg = t >> 6;
        const int di = n0 + col;
        const float c0 = convw_l[di * KK + 0];
        const float c1 = convw_l[di * KK + 1];
        const float c2 = convw_l[di * KK + 2];
        const float cbv = convb_l[di];
        const int l0 = lg * 7;
        float xm2 = (l0 >= 2) ? __bfloat162float(xbt[l0 - 2][col]) : 0.f;
        float xm1 = (l0 >= 1) ? __bfloat162float(xbt[l0 - 1][col]) : 0.f;
        #pragma unroll
        for (int j = 0; j < 7; ++j) {
            const int l = l0 + j;
            const float x0 = __bfloat162float(xbt[l][col]);
            const float v = siluf_(cbv + c0 * xm2 + c1 * xm1 + c2 * x0);
            xm2 = xm1; xm1 = x0;
            ub[(size_t)(b * LL + l) * DI + di] = __float2bfloat16(v);
        }
    } else {
        const int zc = n0 - DI + ncol;
        #pragma unroll
        for (int r = 0; r < 4; ++r) {
            const int m0 = lrow + r, m1 = 16 + lrow + r;
            gzb[(size_t)(b * LL + m0) * DI + zc] = __float2bfloat16(siluf_(acc0[r]));
            if (m1 < LL)
                gzb[(size_t)(b * LL + m1) * DI + zc] = __float2bfloat16(siluf_(acc1[r]));
        }
    }
}

// ---------------- x_proj MFMA ----------------
__global__ __launch_bounds__(256) void k_xproj(
        const __hip_bfloat16* __restrict__ ub,    // [NTOK][DI]
        const __hip_bfloat16* __restrict__ xpw_l, // [NDBC][DI]
        float* __restrict__ dbc) {                // [NTOK][NDBC]
    __shared__ __align__(16) __hip_bfloat16 As[32][520];

    const int m0 = blockIdx.x * 32;
    const int t = threadIdx.x;
    const int wave = t >> 6, lane = t & 63;
    const int rla = lane & 15, koff = (lane >> 4) * 8;
    const int lrow = (lane >> 4) * 4, lcol = lane & 15;

    for (int i = t; i < 32 * 64; i += 256) {
        const int r = i >> 6, c = (i & 63) * 8;
        *(int4*)&As[r][c] = *(const int4*)&ub[(size_t)(m0 + r) * DI + c];
    }
    __syncthreads();

    #pragma unroll
    for (int cc = 0; cc < 2; ++cc) {
        const int c = wave + cc * 4;
        if (c < 6) {
            const int mt = c & 1, nt = c >> 1;
            f32x4 acc = {};
            #pragma unroll
            for (int ks = 0; ks < 16; ++ks) {
                bf16x8 bf = *(const bf16x8*)&xpw_l[(size_t)(nt * 16 + rla) * DI + ks * 32 + koff];
                bf16x8 af = *(const bf16x8*)&As[mt * 16 + rla][ks * 32 + koff];
                acc = __builtin_amdgcn_mfma_f32_16x16x32_bf16(af, bf, acc, 0, 0, 0);
            }
            #pragma unroll
            for (int r = 0; r < 4; ++r)
                dbc[(size_t)(m0 + mt * 16 + lrow + r) * NDBC + nt * 16 + lcol] = acc[r];
        }
    }
}

// ---------------- selective scan ----------------
__global__ __launch_bounds__(256) void k_scan(
        const __hip_bfloat16* __restrict__ ub,    // [NTOK][DI]
        const __hip_bfloat16* __restrict__ gzb,   // [NTOK][DI]
        const float* __restrict__ dbc,            // [NTOK][NDBC]
        const float* __restrict__ dtw_l,          // [DI][DR]
        const float* __restrict__ dtb_l,          // [DI]
        const float* __restrict__ alog_l,         // [DI][DS]
        const float* __restrict__ Dvec_l,         // [DI]
        __hip_bfloat16* __restrict__ yb) {        // [NTOK][DI]
    __shared__ __align__(16) __hip_bfloat16 sus[LL][64];
    __shared__ __align__(16) __hip_bfloat16 sgz[LL][64];
    __shared__ float sdbc[LL][NDBC];
    __shared__ float sdelta[LL][64];
    __shared__ __align__(16) __hip_bfloat16 sy[LL][64];

    const int b = blockIdx.x;
    const int cg = blockIdx.y;
    const int di0 = cg * 64;
    const int t = threadIdx.x;
    const int wave = t >> 6, lane = t & 63;

    for (int i = t; i < 224; i += 256) {
        const int r = i >> 3, c = (i & 7) * 8;
        *(int4*)&sus[r][c] = *(const int4*)&ub[(size_t)(b * LL + r) * DI + di0 + c];
        *(int4*)&sgz[r][c] = *(const int4*)&gzb[(size_t)(b * LL + r) * DI + di0 + c];
    }
    {
        const float4* s4 = (const float4*)(dbc + (size_t)b * LL * NDBC);
        float4* d4 = (float4*)&sdbc[0][0];
        for (int i = t; i < LL * NDBC / 4; i += 256) d4[i] = s4[i];
    }

    float wrow[DR];
    {
        const float4* w4 = (const float4*)(dtw_l + (size_t)(di0 + lane) * DR);
        #pragma unroll
        for (int q = 0; q < DR / 4; ++q) {
            float4 v = w4[q];
            wrow[q * 4 + 0] = v.x; wrow[q * 4 + 1] = v.y;
            wrow[q * 4 + 2] = v.z; wrow[q * 4 + 3] = v.w;
        }
    }
    const float dbias = dtb_l[di0 + lane];
    __syncthreads();

    #pragma unroll
    for (int j = 0; j < 7; ++j) {
        const int l = wave * 7 + j;
        const float4 q0 = *(const float4*)&sdbc[l][0];
        const float4 q1 = *(const float4*)&sdbc[l][4];
        const float4 q2 = *(const float4*)&sdbc[l][8];
        const float4 q3 = *(const float4*)&sdbc[l][12];
        float d0 = wrow[0] * q0.x + wrow[1] * q0.y + wrow[2] * q0.z + wrow[3] * q0.w;
        float d1 = wrow[4] * q1.x + wrow[5] * q1.y + wrow[6] * q1.z + wrow[7] * q1.w;
        float d2 = wrow[8] * q2.x + wrow[9] * q2.y + wrow[10] * q2.z + wrow[11] * q2.w;
        float d3 = wrow[12] * q3.x + wrow[13] * q3.y + wrow[14] * q3.z + wrow[15] * q3.w;
        sdelta[l][lane] = softplus_fast(((d0 + d1) + (d2 + d3)) + dbias);
    }

    const int c = t >> 2, sq = t & 3;
    const int di = di0 + c;
    float4 aq = *(const float4*)&alog_l[(size_t)di * DS + sq * 4];
    const float A0 = -__expf(aq.x), A1 = -__expf(aq.y);
    const float A2 = -__expf(aq.z), A3 = -__expf(aq.w);
    const float Dd = Dvec_l[di];

    __syncthreads();

    float st0 = 0.f, st1 = 0.f, st2 = 0.f, st3 = 0.f;
    #pragma unroll 2
    for (int l = 0; l < LL; ++l) {
        const float d = sdelta[l][c];
        const float uu = __bfloat162float(sus[l][c]);
        const float du = d * uu;
        const float4 Bq = *(const float4*)&sdbc[l][DR + sq * 4];
        const float4 Cq = *(const float4*)&sdbc[l][DR + DS + sq * 4];
        st0 = __expf(d * A0) * st0 + du * Bq.x;
        st1 = __expf(d * A1) * st1 + du * Bq.y;
        st2 = __expf(d * A2) * st2 + du * Bq.z;
        st3 = __expf(d * A3) * st3 + du * Bq.w;
        float yp = st0 * Cq.x + st1 * Cq.y + st2 * Cq.z + st3 * Cq.w;
        yp += __shfl_xor(yp, 1);
        yp += __shfl_xor(yp, 2);
        if (sq == 0) {
            const float g = __bfloat162float(sgz[l][c]);
            sy[l][c] = __float2bfloat16((yp + uu * Dd) * g);
        }
    }
    __syncthreads();

    for (int i = t; i < 224; i += 256) {
        const int r = i >> 3, cc = (i & 7) * 8;
        *(int4*)&yb[(size_t)(b * LL + r) * DI + di0 + cc] = *(const int4*)&sy[r][cc];
    }
}

// ---------------- out_proj; LAST fuses pool+cls ----------------
template <int LAST>
__global__ __launch_bounds__(256) void k_outproj(
        const __hip_bfloat16* __restrict__ yb,    // [NTOK][DI]
        const __hip_bfloat16* __restrict__ opw_l, // [DM][DI]
        float* __restrict__ h,                    // [NTOK][DM]
        __hip_bfloat16* __restrict__ hb,
        const float* __restrict__ clsw,           // [NOUT][DM]
        float* __restrict__ out) {                // [BB][NOUT] (pre-zeroed)
    __shared__ __align__(16) __hip_bfloat16 As[32][520];

    const int b = blockIdx.y;
    const int n0 = blockIdx.x * 32;
    const int t = threadIdx.x;
    const int wave = t >> 6, lane = t & 63;
    const int rla = lane & 15, koff = (lane >> 4) * 8;
    const int lrow = (lane >> 4) * 4, lcol = lane & 15;

    for (int i = t; i < 28 * 64; i += 256) {
        const int r = i >> 6, c = (i & 63) * 8;
        *(int4*)&As[r][c] = *(const int4*)&yb[(size_t)(b * LL + r) * DI + c];
    }
    __syncthreads();

    const int mt = wave & 1, nt = wave >> 1;
    f32x4 acc = {};
    #pragma unroll
    for (int ks = 0; ks < 16; ++ks) {
        bf16x8 bf = *(const bf16x8*)&opw_l[(size_t)(n0 + nt * 16 + rla) * DI + ks * 32 + koff];
        bf16x8 af = *(const bf16x8*)&As[mt * 16 + rla][ks * 32 + koff];
        acc = __builtin_amdgcn_mfma_f32_16x16x32_bf16(af, bf, acc, 0, 0, 0);
    }
    #pragma unroll
    for (int r = 0; r < 4; ++r) {
        const int m = mt * 16 + lrow + r;
        if (m < LL) {
            const int n = n0 + nt * 16 + lcol;
            const size_t idx = (size_t)(b * LL + m) * DM + n;
            const float v = h[idx] + acc[r];
            h[idx] = v;
            hb[idx] = __float2bfloat16(v);
        }
    }

    if (LAST) {
        // fused pool + classifier partial over this block's 32-column slice.
        __shared__ float pooled[32];
        __syncthreads();
        if (t < 32) {
            float p = 0.f;
            for (int l = 0; l < LL; ++l) p += h[(size_t)(b * LL + l) * DM + n0 + t];
            pooled[t] = p * (1.0f / LL);
        }
        __syncthreads();
        if (t < NOUT) {
            const float* cw = clsw + t * DM + n0;
            float a0 = 0.f, a1 = 0.f, a2 = 0.f, a3 = 0.f;
            #pragma unroll
            for (int n = 0; n < 32; n += 4) {
                a0 += pooled[n + 0] * cw[n + 0];
                a1 += pooled[n + 1] * cw[n + 1];
                a2 += pooled[n + 2] * cw[n + 2];
                a3 += pooled[n + 3] * cw[n + 3];
            }
            atomicAdd(&out[b * NOUT + t], (a0 + a1) + (a2 + a3));
        }
    }
}

extern "C" void kernel_launch(void* const* d_in, const int* in_sizes, int n_in,
                              void* d_out, int out_size, void* d_ws, size_t ws_size,
                              hipStream_t stream) {
    const float* x       = (const float*)d_in[0];
    const float* ipw     = (const float*)d_in[1];
    const float* inw     = (const float*)d_in[2];
    const float* convw   = (const float*)d_in[3];
    const float* convb   = (const float*)d_in[4];
    const float* xpw     = (const float*)d_in[5];
    const float* dtw     = (const float*)d_in[6];
    const float* dtb     = (const float*)d_in[7];
    const float* alog    = (const float*)d_in[8];
    const float* Dvec    = (const float*)d_in[9];
    const float* opw     = (const float*)d_in[10];
    const float* clsw    = (const float*)d_in[11];
    float* out = (float*)d_out;

    float* h   = (float*)d_ws;                           // NTOK*DM f32
    float* dbc = h + (size_t)NTOK * DM;                  // NTOK*NDBC f32
    __hip_bfloat16* hb   = (__hip_bfloat16*)(dbc + (size_t)NTOK * NDBC);
    __hip_bfloat16* ub   = hb + (size_t)NTOK * DM;
    __hip_bfloat16* gzb  = ub + (size_t)NTOK * DI;
    __hip_bfloat16* yb   = gzb + (size_t)NTOK * DI;
    __hip_bfloat16* inwb = yb + (size_t)NTOK * DI;
    __hip_bfloat16* opwb = inwb + N_INW;
    __hip_bfloat16* xpwb = opwb + N_OPW;

    // zero out (accumulated via atomics in the last out_proj)
    hipMemsetAsync(out, 0, (size_t)BB * NOUT * sizeof(float), stream);

    hipLaunchKernelGGL(k_prep, dim3(CAST_BLOCKS + INPROJ_BLOCKS), dim3(256), 0, stream,
                       inw, opw, xpw, inwb, opwb, xpwb, x, ipw, h, hb);

    for (int layer = 0; layer < NLAYER; ++layer) {
        const __hip_bfloat16* inwb_l = inwb + (size_t)layer * 2 * DI * DM;
        const __hip_bfloat16* xpwb_l = xpwb + (size_t)layer * NDBC * DI;
        const __hip_bfloat16* opwb_l = opwb + (size_t)layer * DM * DI;
        const float* convw_l = convw + (size_t)layer * DI * KK;
        const float* convb_l = convb + (size_t)layer * DI;
        const float* dtw_l   = dtw  + (size_t)layer * DI * DR;
        const float* dtb_l   = dtb  + (size_t)layer * DI;
        const float* alog_l  = alog + (size_t)layer * DI * DS;
        const float* Dvec_l  = Dvec + (size_t)layer * DI;

        hipLaunchKernelGGL(k_xz_conv, dim3(16, BB), dim3(256), 0, stream,
                           hb, inwb_l, convw_l, convb_l, ub, gzb);

        hipLaunchKernelGGL(k_xproj, dim3(NTOK / 32), dim3(256), 0, stream,
                           ub, xpwb_l, dbc);

        hipLaunchKernelGGL(k_scan, dim3(BB, 8), dim3(256), 0, stream,
                           ub, gzb, dbc, dtw_l, dtb_l, alog_l, Dvec_l, yb);

        if (layer < NLAYER - 1) {
            hipLaunchKernelGGL((k_outproj<0>), dim3(8, BB), dim3(256), 0, stream,
                               yb, opwb_l, h, hb, clsw, out);
        } else {
            hipLaunchKernelGGL((k_outproj<1>), dim3(8, BB), dim3(256), 0, stream,
                               yb, opwb_l, h, hb, clsw, out);
        }
    }
}